// Round 2
// baseline (227.329 us; speedup 1.0000x reference)
//
#include <hip/hip_runtime.h>
#include <stdint.h>

#define V_   6890
#define N3   20670     // 3*V
#define NPAD 20736     // 108*192 padded rows for BextT
#define VPAD 7168      // 448 v-tiles of 16
#define J_   24
#define NB_  10
#define KP   207       // pose-feature K
#define KE   224       // extended K: 207 pose + 10 shape + 1 template + 6 zero
#define LDP  204       // LDS pitch (floats): 16B-aligned rows, conflict-free b128 writes

typedef __attribute__((ext_vector_type(8))) short bf16x8;
typedef __attribute__((ext_vector_type(4))) float f32x4;

__device__ __forceinline__ float bf2f(ushort u) {
    union { uint32_t u; float f; } cv; cv.u = ((uint32_t)u) << 16; return cv.f;
}
__device__ __forceinline__ ushort f2bf(float f) {
    union { float f; uint32_t u; } cv; cv.f = f;
    uint32_t u = cv.u;
    u += 0x7FFFu + ((u >> 16) & 1u);   // round-to-nearest-even
    return (ushort)(u >> 16);
}

// ---------------------------------------------------------------------------
// K1a: JT/JS partial sums over v-chunks of 512
// ---------------------------------------------------------------------------
__global__ __launch_bounds__(256) void k_jreg(const float* __restrict__ jreg,
                                              const float* __restrict__ vt,
                                              const float* __restrict__ sd,
                                              float* __restrict__ jsp) {
    int j = blockIdx.x, c = blockIdx.y;
    int t = threadIdx.x;
    float acc[33];
#pragma unroll
    for (int i = 0; i < 33; i++) acc[i] = 0.f;
#pragma unroll
    for (int it = 0; it < 2; it++) {
        int v = c * 512 + it * 256 + t;
        if (v < V_) {
            float w = jreg[(size_t)j * V_ + v];
            acc[0] += w * vt[v * 3 + 0];
            acc[1] += w * vt[v * 3 + 1];
            acc[2] += w * vt[v * 3 + 2];
            const float* sdv = sd + (size_t)v * 30;
#pragma unroll
            for (int i = 0; i < 30; i++) acc[3 + i] += w * sdv[i];
        }
    }
    __shared__ float red[256][33];
#pragma unroll
    for (int i = 0; i < 33; i++) red[t][i] = acc[i];
    __syncthreads();
    for (int s = 128; s > 0; s >>= 1) {
        if (t < s) {
#pragma unroll
            for (int i = 0; i < 33; i++) red[t][i] += red[t + s][i];
        }
        __syncthreads();
    }
    if (t < 33) jsp[(size_t)(j * 14 + c) * 33 + t] = red[0][t];
}

// K1a2: reduce 14 partials -> js[24*33]
__global__ __launch_bounds__(832) void k_jred(const float* __restrict__ jsp,
                                              float* __restrict__ js) {
    int t = threadIdx.x;
    if (t >= 792) return;
    int j = t / 33, i = t % 33;
    float s = 0.f;
#pragma unroll
    for (int c = 0; c < 14; c++) s += jsp[(size_t)(j * 14 + c) * 33 + i];
    js[t] = s;
}

// ---------------------------------------------------------------------------
// K1b: build BextT[n][k] (bf16, NPAD x 224). Grid (81, 28): 8 k per thread.
// ---------------------------------------------------------------------------
__global__ __launch_bounds__(256) void k_bext(const float* __restrict__ pd,
                                              const float* __restrict__ sd,
                                              const float* __restrict__ vt,
                                              ushort* __restrict__ bt) {
    int n  = blockIdx.x * 256 + threadIdx.x;   // < NPAD
    int k0 = blockIdx.y * 8;
    bool valid = n < N3;
    union { ushort s[8]; uint4 v; } u;
#pragma unroll
    for (int i = 0; i < 8; i++) {
        int k = k0 + i;
        float x = 0.f;
        if (valid) {
            if (k < KP)              x = pd[(size_t)k * N3 + n];
            else if (k < KP + NB_)   x = sd[(size_t)n * NB_ + (k - KP)];
            else if (k == KP + NB_)  x = vt[n];
        }
        u.s[i] = f2bf(x);
    }
    *(uint4*)(bt + (size_t)n * KE + k0) = u.v;   // 16B aligned
}

// ---------------------------------------------------------------------------
// K1c: lbs_weights -> bf16 hi/lo, layout [VPAD][32] (j>=24 and v>=V_ zero)
// ---------------------------------------------------------------------------
__global__ __launch_bounds__(256) void k_wbf(const float* __restrict__ lw,
                                             ushort* __restrict__ w_hi,
                                             ushort* __restrict__ w_lo) {
    int i = blockIdx.x * 256 + threadIdx.x;    // < VPAD*32
    int v = i >> 5, j = i & 31;
    float x = (j < 24 && v < V_) ? lw[(size_t)v * 24 + j] : 0.f;
    ushort hi = f2bf(x);
    w_hi[i] = hi;
    w_lo[i] = f2bf(x - bf2f(hi));
}

// ---------------------------------------------------------------------------
// K2: per-batch — Rodrigues, joints, pose_feat (bf16), FK, then write
// A_rel TRANSPOSED as bf16 hi/lo: aT[b][e*32+j] = A_rel[b][j][e] (e<12,j<24).
// ---------------------------------------------------------------------------
__global__ __launch_bounds__(64) void k_pose(const float* __restrict__ shape,
                                             const float* __restrict__ body_pose,
                                             const float* __restrict__ pelvis,
                                             const float* __restrict__ js,
                                             ushort* __restrict__ pfext,
                                             ushort* __restrict__ aT_hi,
                                             ushort* __restrict__ aT_lo,
                                             int Breal) {
    int b = blockIdx.x;
    int t = threadIdx.x;
    if (b >= Breal) {
        uint32_t* pz = (uint32_t*)(pfext + (size_t)b * KE);
        for (int i = t; i < KE / 2; i += 64) pz[i] = 0;
        return;
    }
    __shared__ float Rs[24][9];
    __shared__ float Js[24][3];
    __shared__ float As[24][12];

    if (t < 24) {
        float rx, ry, rz;
        if (t == 0) {
            rx = pelvis[b * 3 + 0]; ry = pelvis[b * 3 + 1]; rz = pelvis[b * 3 + 2];
        } else {
            const float* p = body_pose + ((size_t)b * 23 + (t - 1)) * 3;
            rx = p[0]; ry = p[1]; rz = p[2];
        }
        float th = sqrtf(rx * rx + ry * ry + rz * rz + 1e-8f);
        float inv = 1.f / th;
        float x = rx * inv, y = ry * inv, z = rz * inv;
        float c = cosf(th), s = sinf(th), omc = 1.f - c;
        float R[9];
        R[0] = c + omc * x * x;     R[1] = omc * x * y - s * z; R[2] = omc * x * z + s * y;
        R[3] = omc * y * x + s * z; R[4] = c + omc * y * y;     R[5] = omc * y * z - s * x;
        R[6] = omc * z * x - s * y; R[7] = omc * z * y + s * x; R[8] = c + omc * z * z;
#pragma unroll
        for (int e = 0; e < 9; e++) Rs[t][e] = R[e];

        const float* jsj = js + t * 33;
        float sh[10];
#pragma unroll
        for (int l = 0; l < 10; l++) sh[l] = shape[b * 10 + l];
#pragma unroll
        for (int c2 = 0; c2 < 3; c2++) {
            float a = jsj[c2];
#pragma unroll
            for (int l = 0; l < 10; l++) a += sh[l] * jsj[3 + c2 * 10 + l];
            Js[t][c2] = a;
        }
        ushort* pf = pfext + (size_t)b * KE;
        if (t >= 1) {
#pragma unroll
            for (int e = 0; e < 9; e++) {
                float v = R[e] - ((e == 0 || e == 4 || e == 8) ? 1.f : 0.f);
                pf[(t - 1) * 9 + e] = f2bf(v);
            }
        } else {
            for (int l = 0; l < 10; l++) pf[KP + l] = f2bf(sh[l]);
            pf[KP + NB_] = 0x3F80;                                   // 1.0 bf16
            for (int k = KP + NB_ + 1; k < KE; k++) pf[k] = 0;
        }
    }
    __syncthreads();

    if (t < 12) {
        int row = t >> 2, col = t & 3;
        As[0][t] = (col < 3) ? Rs[0][row * 3 + col] : Js[0][row];
    }
    __syncthreads();
    const int par[24] = {-1,0,0,0,1,2,3,4,5,6,7,8,9,9,9,12,13,14,16,17,18,19,20,21};
#pragma unroll 1
    for (int j = 1; j < 24; j++) {
        int p = par[j];
        float val = 0.f;
        if (t < 12) {
            int row = t >> 2, col = t & 3;
            if (col < 3) {
                val = As[p][row * 4 + 0] * Rs[j][0 * 3 + col]
                    + As[p][row * 4 + 1] * Rs[j][1 * 3 + col]
                    + As[p][row * 4 + 2] * Rs[j][2 * 3 + col];
            } else {
                float relx = Js[j][0] - Js[p][0];
                float rely = Js[j][1] - Js[p][1];
                float relz = Js[j][2] - Js[p][2];
                val = As[p][row * 4 + 0] * relx + As[p][row * 4 + 1] * rely
                    + As[p][row * 4 + 2] * relz + As[p][row * 4 + 3];
            }
        }
        __syncthreads();
        if (t < 12) As[j][t] = val;
        __syncthreads();
    }
    // finalize t_corr in place: As[j][x*4+3] = t - R*joint
    if (t < 24) {
        float tc[3];
#pragma unroll
        for (int row = 0; row < 3; row++) {
            float r0 = As[t][row * 4 + 0], r1 = As[t][row * 4 + 1], r2 = As[t][row * 4 + 2];
            tc[row] = As[t][row * 4 + 3] - (r0 * Js[t][0] + r1 * Js[t][1] + r2 * Js[t][2]);
        }
        As[t][3] = tc[0]; As[t][7] = tc[1]; As[t][11] = tc[2];
    }
    __syncthreads();
    // aT[e*32+j] = As[j][e], hi/lo bf16 (e<12, j<24; else 0)
    ushort* dh = aT_hi + (size_t)b * 512;
    ushort* dl = aT_lo + (size_t)b * 512;
    for (int i = t; i < 512; i += 64) {
        int e = i >> 5, j = i & 31;
        float val = (e < 12 && j < 24) ? As[j][e] : 0.f;
        ushort hi = f2bf(val);
        dh[i] = hi;
        dl[i] = f2bf(val - bf2f(hi));
    }
}

// ---------------------------------------------------------------------------
// K3+K4 fused v2: per block, a 64-vertex x 32-batch tile (LDS 26.1 KB ->
// 6 blocks/CU = 24 waves, vs 3/12 before).  Wave wv: bh = wv&1 (batch half),
// nh = wv>>1 (n half).
// Stage 1 (per wave): v_posed[96n x 16b] via MFMA (A = bt rows, B = pfext
//   rows, K = 224, 6 frags) -> LDS posed[32][204] fp32, written as 16B-
//   aligned f32x4 (conflict-free: bank groups 4*((3m+q)&7) get 8 lanes each).
// NO __syncthreads: each wave's stage-2 reads exactly the LDS region it
//   wrote (rows bh*16+bb, cols nh*96..+95) -> wave-local s_waitcnt lgkmcnt(0).
// Stage 2 (per wave, its 16 batches, depth-1 prefetch of Ah/Al):
//   Tv^T = A_b'(16e x 32j) @ W^T(32j x 16v) via 3 MFMAs (hi*hi+lo*hi+hi*lo);
//   quad q<3 holds row q: verts[v,q] = acc0*p0+acc1*p1+acc2*p2+acc3+trans[q],
//   p from LDS (bank 3m mod 32, broadcast across quads, conflict-free).
// Grid: 1D 108*NY blocks (NY = Bpad/32), bijective XCD swizzle (nwg%8==0)
//   so each XCD's L2 keeps its ~1.2 MB bt slice + 2 MB aT hot.
// ---------------------------------------------------------------------------
__global__ __launch_bounds__(256) void k_fused(const ushort* __restrict__ bt,
                                               const ushort* __restrict__ pfext,
                                               const ushort* __restrict__ aT_hi,
                                               const ushort* __restrict__ aT_lo,
                                               const ushort* __restrict__ w_hi,
                                               const ushort* __restrict__ w_lo,
                                               const float* __restrict__ trans,
                                               float* __restrict__ vert,
                                               int Breal, int NY) {
    int lane = threadIdx.x & 63;
    int wv   = threadIdx.x >> 6;
    int quad = lane >> 4;
    int m    = lane & 15;
    int bh   = wv & 1;
    int nh   = wv >> 1;

    // bijective XCD swizzle: nwg = 108*NY (NY even) is divisible by 8
    int bid = blockIdx.x;
    int cpx = (108 * NY) >> 3;
    int sw  = (bid & 7) * cpx + (bid >> 3);
    unsigned uNY = (unsigned)NY;
    int vtile = (int)((unsigned)sw / uNY);        // 0..107
    int by    = sw - vtile * NY;

    int nbase_w = vtile * 192 + nh * 96;
    int bbase_w = by * 32 + bh * 16;              // this wave's 16 batches

    __shared__ __align__(16) float posed[32][LDP];

    // hoist W frags (global loads overlap stage-1 compute)
    bf16x8 Wh[2], Wl[2];
#pragma unroll
    for (int i = 0; i < 2; i++) {
        size_t offw = (size_t)((vtile * 4 + nh * 2 + i) * 16 + m) * 32 + quad * 8;
        Wh[i] = *(const bf16x8*)(w_hi + offw);
        Wl[i] = *(const bf16x8*)(w_lo + offw);
    }

    // ---- stage 1: v_posed GEMM (96n x 16b per wave) ----
    f32x4 acc[6];
#pragma unroll
    for (int f = 0; f < 6; f++) acc[f] = (f32x4){0.f, 0.f, 0.f, 0.f};

    const ushort* bp = pfext + (size_t)(bbase_w + m) * KE + quad * 8;
    const ushort* ap = bt + (size_t)(nbase_w + m) * KE + quad * 8;
#pragma unroll 2
    for (int ks = 0; ks < 7; ks++) {
        bf16x8 bfrag = *(const bf16x8*)(bp + ks * 32);
#pragma unroll
        for (int f = 0; f < 6; f++) {
            bf16x8 afrag = *(const bf16x8*)(ap + (size_t)(f * 16) * KE + ks * 32);
            acc[f] = __builtin_amdgcn_mfma_f32_16x16x32_bf16(afrag, bfrag, acc[f], 0, 0, 0);
        }
    }
    // scatter fragments: 16B-aligned vector writes, conflict-free
#pragma unroll
    for (int f = 0; f < 6; f++)
        *(f32x4*)&posed[bh * 16 + m][nh * 96 + f * 16 + quad * 4] = acc[f];

    // wave-private LDS region: wave-local drain instead of block barrier
    __asm volatile("s_waitcnt lgkmcnt(0)" ::: "memory");

    // ---- stage 2: LBS over this wave's 16 batches ----
    int col0 = nh * 96 + 3 * m;
    size_t aoff0 = (size_t)bbase_w * 512 + m * 32 + quad * 8;
    bf16x8 Ah = *(const bf16x8*)(aT_hi + aoff0);
    bf16x8 Al = *(const bf16x8*)(aT_lo + aoff0);

#pragma unroll 1
    for (int bb = 0; bb < 16; bb++) {
        int b = bbase_w + bb;
        if (b >= Breal) break;
        // depth-1 prefetch of next batch's transform
        int bn = (bb < 15 && b + 1 < Breal) ? b + 1 : b;
        size_t aoffn = (size_t)bn * 512 + m * 32 + quad * 8;
        bf16x8 Ah_n = *(const bf16x8*)(aT_hi + aoffn);
        bf16x8 Al_n = *(const bf16x8*)(aT_lo + aoffn);
        float tq = (quad < 3) ? trans[b * 3 + quad] : 0.f;
        const float* pr = &posed[bh * 16 + bb][0];
        float* vrow = vert + (size_t)b * N3;
#pragma unroll
        for (int i = 0; i < 2; i++) {
            int vloc = nh * 32 + i * 16 + m;
            int v = vtile * 64 + vloc;
            float p0 = pr[col0 + i * 48 + 0];
            float p1 = pr[col0 + i * 48 + 1];
            float p2 = pr[col0 + i * 48 + 2];
            f32x4 a2 = (f32x4){0.f, 0.f, 0.f, 0.f};
            a2 = __builtin_amdgcn_mfma_f32_16x16x32_bf16(Ah, Wh[i], a2, 0, 0, 0);
            a2 = __builtin_amdgcn_mfma_f32_16x16x32_bf16(Al, Wh[i], a2, 0, 0, 0);
            a2 = __builtin_amdgcn_mfma_f32_16x16x32_bf16(Ah, Wl[i], a2, 0, 0, 0);
            float res = a2[0] * p0 + a2[1] * p1 + a2[2] * p2 + a2[3] + tq;
            if (quad < 3 && v < V_)
                vrow[3 * v + quad] = res;
        }
        Ah = Ah_n; Al = Al_n;
    }
}

// ---------------------------------------------------------------------------
extern "C" void kernel_launch(void* const* d_in, const int* in_sizes, int n_in,
                              void* d_out, int out_size, void* d_ws, size_t ws_size,
                              hipStream_t stream) {
    const float* shape = (const float*)d_in[0];
    const float* bpose = (const float*)d_in[1];
    const float* pelv  = (const float*)d_in[2];
    const float* trans = (const float*)d_in[3];
    const float* vt    = (const float*)d_in[4];
    const float* sd    = (const float*)d_in[5];
    const float* pd    = (const float*)d_in[6];
    const float* lw    = (const float*)d_in[7];
    const float* jr    = (const float*)d_in[8];
    float* out = (float*)d_out;

    int B    = in_sizes[0] / NB_;          // batch from shape (B,10)
    int Bpad = (B + 63) & ~63;
    int NY   = Bpad / 32;

    char* ws = (char*)d_ws;
    size_t off = 0;
    auto alloc = [&](size_t bytes) { char* p = ws + off; off += (bytes + 255) & ~(size_t)255; return p; };
    float*  jsp   = (float*) alloc(24 * 14 * 33 * 4);
    float*  js    = (float*) alloc(24 * 33 * 4);
    ushort* pfext = (ushort*)alloc((size_t)Bpad * KE * 2);
    ushort* aT_hi = (ushort*)alloc((size_t)B * 512 * 2);
    ushort* aT_lo = (ushort*)alloc((size_t)B * 512 * 2);
    ushort* w_hi  = (ushort*)alloc((size_t)VPAD * 32 * 2);
    ushort* w_lo  = (ushort*)alloc((size_t)VPAD * 32 * 2);
    ushort* bt    = (ushort*)alloc((size_t)NPAD * KE * 2);

    k_jreg<<<dim3(24, 14), 256, 0, stream>>>(jr, vt, sd, jsp);
    k_jred<<<1, 832, 0, stream>>>(jsp, js);
    k_bext<<<dim3(NPAD / 256, KE / 8), 256, 0, stream>>>(pd, sd, vt, bt);
    k_wbf<<<VPAD * 32 / 256, 256, 0, stream>>>(lw, w_hi, w_lo);
    k_pose<<<Bpad, 64, 0, stream>>>(shape, bpose, pelv, js, pfext, aT_hi, aT_lo, B);
    k_fused<<<dim3(108 * NY), 256, 0, stream>>>(bt, pfext, aT_hi, aT_lo,
                                                w_hi, w_lo, trans, out, B, NY);
}

// Round 3
// 225.931 us; speedup vs baseline: 1.0062x; 1.0062x over previous
//
#include <hip/hip_runtime.h>
#include <stdint.h>

#define V_   6890
#define N3   20670     // 3*V
#define NPAD 20736     // 108*192 padded rows for BextT
#define VPAD 7168      // 448 v-tiles of 16
#define J_   24
#define NB_  10
#define KP   207       // pose-feature K
#define KE   224       // extended K: 207 pose + 10 shape + 1 template + 6 zero
#define LDP  204       // LDS pitch (floats): 16B-aligned rows, spread b128 writes

typedef __attribute__((ext_vector_type(8))) short bf16x8;
typedef __attribute__((ext_vector_type(4))) float f32x4;

__device__ __forceinline__ float bf2f(ushort u) {
    union { uint32_t u; float f; } cv; cv.u = ((uint32_t)u) << 16; return cv.f;
}
__device__ __forceinline__ ushort f2bf(float f) {
    union { float f; uint32_t u; } cv; cv.f = f;
    uint32_t u = cv.u;
    u += 0x7FFFu + ((u >> 16) & 1u);   // round-to-nearest-even
    return (ushort)(u >> 16);
}

// ---------------------------------------------------------------------------
// K1a: JT/JS partial sums over v-chunks of 512
// ---------------------------------------------------------------------------
__global__ __launch_bounds__(256) void k_jreg(const float* __restrict__ jreg,
                                              const float* __restrict__ vt,
                                              const float* __restrict__ sd,
                                              float* __restrict__ jsp) {
    int j = blockIdx.x, c = blockIdx.y;
    int t = threadIdx.x;
    float acc[33];
#pragma unroll
    for (int i = 0; i < 33; i++) acc[i] = 0.f;
#pragma unroll
    for (int it = 0; it < 2; it++) {
        int v = c * 512 + it * 256 + t;
        if (v < V_) {
            float w = jreg[(size_t)j * V_ + v];
            acc[0] += w * vt[v * 3 + 0];
            acc[1] += w * vt[v * 3 + 1];
            acc[2] += w * vt[v * 3 + 2];
            const float* sdv = sd + (size_t)v * 30;
#pragma unroll
            for (int i = 0; i < 30; i++) acc[3 + i] += w * sdv[i];
        }
    }
    __shared__ float red[256][33];
#pragma unroll
    for (int i = 0; i < 33; i++) red[t][i] = acc[i];
    __syncthreads();
    for (int s = 128; s > 0; s >>= 1) {
        if (t < s) {
#pragma unroll
            for (int i = 0; i < 33; i++) red[t][i] += red[t + s][i];
        }
        __syncthreads();
    }
    if (t < 33) jsp[(size_t)(j * 14 + c) * 33 + t] = red[0][t];
}

// ---------------------------------------------------------------------------
// K1b: merged prep — role-split single launch:
//   blocks [0, 2268):  build BextT[n][k] (bf16, NPAD x 224), 8 k per thread
//   blocks [2268, 3164): lbs_weights -> bf16 hi/lo, layout [VPAD][32]
// ---------------------------------------------------------------------------
__global__ __launch_bounds__(256) void k_prep(const float* __restrict__ pd,
                                              const float* __restrict__ sd,
                                              const float* __restrict__ vt,
                                              const float* __restrict__ lw,
                                              ushort* __restrict__ bt,
                                              ushort* __restrict__ w_hi,
                                              ushort* __restrict__ w_lo) {
    int g = blockIdx.x;
    int t = threadIdx.x;
    if (g < 81 * 28) {
        int nblk = g % 81, kblk = g / 81;
        int n  = nblk * 256 + t;               // < NPAD
        int k0 = kblk * 8;
        bool valid = n < N3;
        union { ushort s[8]; uint4 v; } u;
#pragma unroll
        for (int i = 0; i < 8; i++) {
            int k = k0 + i;
            float x = 0.f;
            if (valid) {
                if (k < KP)              x = pd[(size_t)k * N3 + n];
                else if (k < KP + NB_)   x = sd[(size_t)n * NB_ + (k - KP)];
                else if (k == KP + NB_)  x = vt[n];
            }
            u.s[i] = f2bf(x);
        }
        *(uint4*)(bt + (size_t)n * KE + k0) = u.v;   // 16B aligned
    } else {
        int i = (g - 81 * 28) * 256 + t;       // < VPAD*32
        int v = i >> 5, j = i & 31;
        float x = (j < 24 && v < V_) ? lw[(size_t)v * 24 + j] : 0.f;
        ushort hi = f2bf(x);
        w_hi[i] = hi;
        w_lo[i] = f2bf(x - bf2f(hi));
    }
}

// ---------------------------------------------------------------------------
// K2: per-batch — jsp reduce (folded k_jred, same summation order ->
// bit-identical), Rodrigues, joints, pose_feat (bf16), FK, then write
// A_rel TRANSPOSED as bf16 hi/lo: aT[b][e*32+j] = A_rel[b][j][e] (e<12,j<24).
// ---------------------------------------------------------------------------
__global__ __launch_bounds__(64) void k_pose(const float* __restrict__ shape,
                                             const float* __restrict__ body_pose,
                                             const float* __restrict__ pelvis,
                                             const float* __restrict__ jsp,
                                             ushort* __restrict__ pfext,
                                             ushort* __restrict__ aT_hi,
                                             ushort* __restrict__ aT_lo,
                                             int Breal) {
    int b = blockIdx.x;
    int t = threadIdx.x;
    if (b >= Breal) {
        uint32_t* pz = (uint32_t*)(pfext + (size_t)b * KE);
        for (int i = t; i < KE / 2; i += 64) pz[i] = 0;
        return;
    }
    __shared__ float js_s[792];
    __shared__ float Rs[24][9];
    __shared__ float Js[24][3];
    __shared__ float As[24][12];

    // folded k_jred: js_s[j*33+i] = sum_c jsp[(j*14+c)*33+i]  (c ascending)
    for (int idx = t; idx < 792; idx += 64) {
        int j = idx / 33, i = idx - j * 33;
        float s = 0.f;
#pragma unroll
        for (int c = 0; c < 14; c++) s += jsp[(size_t)(j * 14 + c) * 33 + i];
        js_s[idx] = s;
    }
    __syncthreads();

    if (t < 24) {
        float rx, ry, rz;
        if (t == 0) {
            rx = pelvis[b * 3 + 0]; ry = pelvis[b * 3 + 1]; rz = pelvis[b * 3 + 2];
        } else {
            const float* p = body_pose + ((size_t)b * 23 + (t - 1)) * 3;
            rx = p[0]; ry = p[1]; rz = p[2];
        }
        float th = sqrtf(rx * rx + ry * ry + rz * rz + 1e-8f);
        float inv = 1.f / th;
        float x = rx * inv, y = ry * inv, z = rz * inv;
        float c = cosf(th), s = sinf(th), omc = 1.f - c;
        float R[9];
        R[0] = c + omc * x * x;     R[1] = omc * x * y - s * z; R[2] = omc * x * z + s * y;
        R[3] = omc * y * x + s * z; R[4] = c + omc * y * y;     R[5] = omc * y * z - s * x;
        R[6] = omc * z * x - s * y; R[7] = omc * z * y + s * x; R[8] = c + omc * z * z;
#pragma unroll
        for (int e = 0; e < 9; e++) Rs[t][e] = R[e];

        const float* jsj = js_s + t * 33;
        float sh[10];
#pragma unroll
        for (int l = 0; l < 10; l++) sh[l] = shape[b * 10 + l];
#pragma unroll
        for (int c2 = 0; c2 < 3; c2++) {
            float a = jsj[c2];
#pragma unroll
            for (int l = 0; l < 10; l++) a += sh[l] * jsj[3 + c2 * 10 + l];
            Js[t][c2] = a;
        }
        ushort* pf = pfext + (size_t)b * KE;
        if (t >= 1) {
#pragma unroll
            for (int e = 0; e < 9; e++) {
                float v = R[e] - ((e == 0 || e == 4 || e == 8) ? 1.f : 0.f);
                pf[(t - 1) * 9 + e] = f2bf(v);
            }
        } else {
            for (int l = 0; l < 10; l++) pf[KP + l] = f2bf(sh[l]);
            pf[KP + NB_] = 0x3F80;                                   // 1.0 bf16
            for (int k = KP + NB_ + 1; k < KE; k++) pf[k] = 0;
        }
    }
    __syncthreads();

    if (t < 12) {
        int row = t >> 2, col = t & 3;
        As[0][t] = (col < 3) ? Rs[0][row * 3 + col] : Js[0][row];
    }
    __syncthreads();
    const int par[24] = {-1,0,0,0,1,2,3,4,5,6,7,8,9,9,9,12,13,14,16,17,18,19,20,21};
#pragma unroll 1
    for (int j = 1; j < 24; j++) {
        int p = par[j];
        float val = 0.f;
        if (t < 12) {
            int row = t >> 2, col = t & 3;
            if (col < 3) {
                val = As[p][row * 4 + 0] * Rs[j][0 * 3 + col]
                    + As[p][row * 4 + 1] * Rs[j][1 * 3 + col]
                    + As[p][row * 4 + 2] * Rs[j][2 * 3 + col];
            } else {
                float relx = Js[j][0] - Js[p][0];
                float rely = Js[j][1] - Js[p][1];
                float relz = Js[j][2] - Js[p][2];
                val = As[p][row * 4 + 0] * relx + As[p][row * 4 + 1] * rely
                    + As[p][row * 4 + 2] * relz + As[p][row * 4 + 3];
            }
        }
        __syncthreads();
        if (t < 12) As[j][t] = val;
        __syncthreads();
    }
    // finalize t_corr in place: As[j][x*4+3] = t - R*joint
    if (t < 24) {
        float tc[3];
#pragma unroll
        for (int row = 0; row < 3; row++) {
            float r0 = As[t][row * 4 + 0], r1 = As[t][row * 4 + 1], r2 = As[t][row * 4 + 2];
            tc[row] = As[t][row * 4 + 3] - (r0 * Js[t][0] + r1 * Js[t][1] + r2 * Js[t][2]);
        }
        As[t][3] = tc[0]; As[t][7] = tc[1]; As[t][11] = tc[2];
    }
    __syncthreads();
    // aT[e*32+j] = As[j][e], hi/lo bf16 (e<12, j<24; else 0)
    ushort* dh = aT_hi + (size_t)b * 512;
    ushort* dl = aT_lo + (size_t)b * 512;
    for (int i = t; i < 512; i += 64) {
        int e = i >> 5, j = i & 31;
        float val = (e < 12 && j < 24) ? As[j][e] : 0.f;
        ushort hi = f2bf(val);
        dh[i] = hi;
        dl[i] = f2bf(val - bf2f(hi));
    }
}

// ---------------------------------------------------------------------------
// K3+K4 fused v3: R1 tile (64v x 64b per block, 3 blocks/CU) + ILP fixes.
// Per wave: stage 1 computes v_posed[192n x 16b] (12 frags, K=224) -> LDS
//   posed[64][204] via 16B f32x4 writes (banks 12m+4q spread; no scalar
//   scatter conflicts). Rows wv*16.. are wave-private -> NO block barrier,
//   just wave-local lgkmcnt(0) ("memory" clobber orders ds ops).
// Stage 2 processes its 16 batches TWO AT A TIME: two independent 3-MFMA
//   chains in flight (breaks the serial-chain latency wall seen in R1/R2),
//   with depth-2 prefetch of aT hi/lo.
// Grid: 1D 108*NYB, bijective XCD swizzle (nwg%8==0): each XCD keeps its
//   ~1.2 MB bt slice hot in L2.
// ---------------------------------------------------------------------------
__global__ __launch_bounds__(256) void k_fused(const ushort* __restrict__ bt,
                                               const ushort* __restrict__ pfext,
                                               const ushort* __restrict__ aT_hi,
                                               const ushort* __restrict__ aT_lo,
                                               const ushort* __restrict__ w_hi,
                                               const ushort* __restrict__ w_lo,
                                               const float* __restrict__ trans,
                                               float* __restrict__ vert,
                                               int Breal, int NYB) {
    int lane = threadIdx.x & 63;
    int wv   = threadIdx.x >> 6;
    int quad = lane >> 4;
    int m    = lane & 15;

    // bijective XCD swizzle: nwg = 108*NYB divisible by 8
    int bid = blockIdx.x;
    int cpx = (108 * NYB) >> 3;
    int sw  = (bid & 7) * cpx + (bid >> 3);
    unsigned uNYB = (unsigned)NYB;
    int vtile = (int)((unsigned)sw / uNYB);       // 0..107
    int by    = sw - vtile * NYB;

    int nbase   = vtile * 192;
    int bbase_w = by * 64 + wv * 16;              // this wave's 16 batches

    __shared__ __align__(16) float posed[64][LDP];

    // hoist W frags (overlap with stage-1 loads)
    bf16x8 Wh[4], Wl[4];
#pragma unroll
    for (int i = 0; i < 4; i++) {
        size_t offw = (size_t)((vtile * 4 + i) * 16 + m) * 32 + quad * 8;
        Wh[i] = *(const bf16x8*)(w_hi + offw);
        Wl[i] = *(const bf16x8*)(w_lo + offw);
    }

    // ---- stage 1: v_posed GEMM (192n x 16b per wave) ----
    f32x4 acc[12];
#pragma unroll
    for (int f = 0; f < 12; f++) acc[f] = (f32x4){0.f, 0.f, 0.f, 0.f};

    const ushort* bp = pfext + (size_t)(bbase_w + m) * KE + quad * 8;
    const ushort* ap = bt + (size_t)(nbase + m) * KE + quad * 8;
#pragma unroll 2
    for (int ks = 0; ks < 7; ks++) {
        bf16x8 bfrag = *(const bf16x8*)(bp + ks * 32);
#pragma unroll
        for (int f = 0; f < 12; f++) {
            bf16x8 afrag = *(const bf16x8*)(ap + (size_t)(f * 16) * KE + ks * 32);
            acc[f] = __builtin_amdgcn_mfma_f32_16x16x32_bf16(afrag, bfrag, acc[f], 0, 0, 0);
        }
    }
    // vector scatter to LDS: banks (12m+4q+16f) mod 32 — spread, no scalar scatter
#pragma unroll
    for (int f = 0; f < 12; f++)
        *(f32x4*)&posed[wv * 16 + m][f * 16 + quad * 4] = acc[f];

    // wave-private LDS rows: wave-local drain instead of block barrier
    __asm volatile("s_waitcnt lgkmcnt(0)" ::: "memory");

    // ---- stage 2: LBS, 2 batches in flight ----
    size_t fragoff = (size_t)m * 32 + quad * 8;
    auto aoff = [&](int bb) {
        int b = bbase_w + bb;
        if (b >= Breal) b = Breal - 1;             // clamp (stores predicated)
        return (size_t)b * 512 + fragoff;
    };

    bf16x8 Ah0 = *(const bf16x8*)(aT_hi + aoff(0));
    bf16x8 Al0 = *(const bf16x8*)(aT_lo + aoff(0));
    bf16x8 Ah1 = *(const bf16x8*)(aT_hi + aoff(1));
    bf16x8 Al1 = *(const bf16x8*)(aT_lo + aoff(1));

#pragma unroll 1
    for (int bb = 0; bb < 16; bb += 2) {
        // depth-2 prefetch (harmless refetch on last iteration)
        int pf = (bb + 2 < 16) ? bb + 2 : bb;
        bf16x8 AhN0 = *(const bf16x8*)(aT_hi + aoff(pf));
        bf16x8 AlN0 = *(const bf16x8*)(aT_lo + aoff(pf));
        bf16x8 AhN1 = *(const bf16x8*)(aT_hi + aoff(pf + 1));
        bf16x8 AlN1 = *(const bf16x8*)(aT_lo + aoff(pf + 1));

        int b0 = bbase_w + bb, b1 = b0 + 1;
        float tq0 = 0.f, tq1 = 0.f;
        if (quad < 3) {
            if (b0 < Breal) tq0 = trans[b0 * 3 + quad];
            if (b1 < Breal) tq1 = trans[b1 * 3 + quad];
        }
        const float* pr0 = &posed[wv * 16 + bb][0];
        const float* pr1 = &posed[wv * 16 + bb + 1][0];
        float* vrow0 = vert + (size_t)b0 * N3;
        float* vrow1 = vert + (size_t)b1 * N3;
#pragma unroll
        for (int i = 0; i < 4; i++) {
            int vloc = i * 16 + m;
            int v = vtile * 64 + vloc;
            int c0 = vloc * 3;
            float p00 = pr0[c0], p01 = pr0[c0 + 1], p02 = pr0[c0 + 2];
            float p10 = pr1[c0], p11 = pr1[c0 + 1], p12 = pr1[c0 + 2];
            f32x4 a20 = (f32x4){0.f, 0.f, 0.f, 0.f};
            f32x4 a21 = (f32x4){0.f, 0.f, 0.f, 0.f};
            a20 = __builtin_amdgcn_mfma_f32_16x16x32_bf16(Ah0, Wh[i], a20, 0, 0, 0);
            a21 = __builtin_amdgcn_mfma_f32_16x16x32_bf16(Ah1, Wh[i], a21, 0, 0, 0);
            a20 = __builtin_amdgcn_mfma_f32_16x16x32_bf16(Al0, Wh[i], a20, 0, 0, 0);
            a21 = __builtin_amdgcn_mfma_f32_16x16x32_bf16(Al1, Wh[i], a21, 0, 0, 0);
            a20 = __builtin_amdgcn_mfma_f32_16x16x32_bf16(Ah0, Wl[i], a20, 0, 0, 0);
            a21 = __builtin_amdgcn_mfma_f32_16x16x32_bf16(Ah1, Wl[i], a21, 0, 0, 0);
            float res0 = a20[0] * p00 + a20[1] * p01 + a20[2] * p02 + a20[3] + tq0;
            float res1 = a21[0] * p10 + a21[1] * p11 + a21[2] * p12 + a21[3] + tq1;
            if (quad < 3 && v < V_) {
                if (b0 < Breal) vrow0[3 * v + quad] = res0;
                if (b1 < Breal) vrow1[3 * v + quad] = res1;
            }
        }
        Ah0 = AhN0; Al0 = AlN0; Ah1 = AhN1; Al1 = AlN1;
    }
}

// ---------------------------------------------------------------------------
extern "C" void kernel_launch(void* const* d_in, const int* in_sizes, int n_in,
                              void* d_out, int out_size, void* d_ws, size_t ws_size,
                              hipStream_t stream) {
    const float* shape = (const float*)d_in[0];
    const float* bpose = (const float*)d_in[1];
    const float* pelv  = (const float*)d_in[2];
    const float* trans = (const float*)d_in[3];
    const float* vt    = (const float*)d_in[4];
    const float* sd    = (const float*)d_in[5];
    const float* pd    = (const float*)d_in[6];
    const float* lw    = (const float*)d_in[7];
    const float* jr    = (const float*)d_in[8];
    float* out = (float*)d_out;

    int B    = in_sizes[0] / NB_;          // batch from shape (B,10)
    int Bpad = (B + 63) & ~63;
    int NYB  = Bpad / 64;

    char* ws = (char*)d_ws;
    size_t off = 0;
    auto alloc = [&](size_t bytes) { char* p = ws + off; off += (bytes + 255) & ~(size_t)255; return p; };
    float*  jsp   = (float*) alloc(24 * 14 * 33 * 4);
    ushort* pfext = (ushort*)alloc((size_t)Bpad * KE * 2);
    ushort* aT_hi = (ushort*)alloc((size_t)B * 512 * 2);
    ushort* aT_lo = (ushort*)alloc((size_t)B * 512 * 2);
    ushort* w_hi  = (ushort*)alloc((size_t)VPAD * 32 * 2);
    ushort* w_lo  = (ushort*)alloc((size_t)VPAD * 32 * 2);
    ushort* bt    = (ushort*)alloc((size_t)NPAD * KE * 2);

    k_jreg<<<dim3(24, 14), 256, 0, stream>>>(jr, vt, sd, jsp);
    k_prep<<<81 * 28 + VPAD * 32 / 256, 256, 0, stream>>>(pd, sd, vt, lw, bt, w_hi, w_lo);
    k_pose<<<Bpad, 64, 0, stream>>>(shape, bpose, pelv, jsp, pfext, aT_hi, aT_lo, B);
    k_fused<<<dim3(108 * NYB), 256, 0, stream>>>(bt, pfext, aT_hi, aT_lo,
                                                 w_hi, w_lo, trans, out, B, NYB);
}

// Round 4
// 207.724 us; speedup vs baseline: 1.0944x; 1.0876x over previous
//
#include <hip/hip_runtime.h>
#include <stdint.h>

#define V_   6890
#define N3   20670     // 3*V
#define NPAD 20736     // 108*192 padded rows for BextT
#define VPAD 7168      // 448 v-tiles of 16
#define J_   24
#define NB_  10
#define KP   207       // pose-feature K
#define KE   224       // extended K: 207 pose + 10 shape + 1 template + 6 zero
#define LDP  201       // LDS pitch (floats), R1-proven

typedef __attribute__((ext_vector_type(8))) short bf16x8;
typedef __attribute__((ext_vector_type(4))) float f32x4;

__device__ __forceinline__ float bf2f(ushort u) {
    union { uint32_t u; float f; } cv; cv.u = ((uint32_t)u) << 16; return cv.f;
}
__device__ __forceinline__ ushort f2bf(float f) {
    union { float f; uint32_t u; } cv; cv.f = f;
    uint32_t u = cv.u;
    u += 0x7FFFu + ((u >> 16) & 1u);   // round-to-nearest-even
    return (ushort)(u >> 16);
}

// ---------------------------------------------------------------------------
// K_pre: role-split single launch (independent work overlaps on-GPU):
//   blocks [0, 336):            jreg partial sums (j = g%24, c = g/24)
//   blocks [336, 336+2268):     build BextT[n][k] (bf16, NPAD x 224)
//   blocks [336+2268, +896):    lbs_weights -> bf16 hi/lo, [VPAD][32]
// jreg reduction done in 3 chunks of 11 over red[256][11] (11.3 KB LDS so
// prep blocks aren't LDS-capped); per-element tree order identical to the
// original [256][33] version -> bit-identical jsp.
// ---------------------------------------------------------------------------
__global__ __launch_bounds__(256) void k_pre(const float* __restrict__ jreg,
                                             const float* __restrict__ vt,
                                             const float* __restrict__ sd,
                                             const float* __restrict__ pd,
                                             const float* __restrict__ lw,
                                             float* __restrict__ jsp,
                                             ushort* __restrict__ bt,
                                             ushort* __restrict__ w_hi,
                                             ushort* __restrict__ w_lo) {
    int g = blockIdx.x;
    int t = threadIdx.x;
    if (g < 336) {
        int j = g % 24, c = g / 24;
        float acc[33];
#pragma unroll
        for (int i = 0; i < 33; i++) acc[i] = 0.f;
#pragma unroll
        for (int it = 0; it < 2; it++) {
            int v = c * 512 + it * 256 + t;
            if (v < V_) {
                float w = jreg[(size_t)j * V_ + v];
                acc[0] += w * vt[v * 3 + 0];
                acc[1] += w * vt[v * 3 + 1];
                acc[2] += w * vt[v * 3 + 2];
                const float* sdv = sd + (size_t)v * 30;
#pragma unroll
                for (int i = 0; i < 30; i++) acc[3 + i] += w * sdv[i];
            }
        }
        __shared__ float red[256][11];
#pragma unroll 1
        for (int ch = 0; ch < 3; ch++) {
#pragma unroll
            for (int i = 0; i < 11; i++) red[t][i] = acc[ch * 11 + i];
            __syncthreads();
            for (int s = 128; s > 0; s >>= 1) {
                if (t < s) {
#pragma unroll
                    for (int i = 0; i < 11; i++) red[t][i] += red[t + s][i];
                }
                __syncthreads();
            }
            if (t < 11) jsp[(size_t)(j * 14 + c) * 33 + ch * 11 + t] = red[0][t];
            __syncthreads();
        }
    } else if (g < 336 + 81 * 28) {
        int gg = g - 336;
        int nblk = gg % 81, kblk = gg / 81;
        int n  = nblk * 256 + t;               // < NPAD
        int k0 = kblk * 8;
        bool valid = n < N3;
        union { ushort s[8]; uint4 v; } u;
#pragma unroll
        for (int i = 0; i < 8; i++) {
            int k = k0 + i;
            float x = 0.f;
            if (valid) {
                if (k < KP)              x = pd[(size_t)k * N3 + n];
                else if (k < KP + NB_)   x = sd[(size_t)n * NB_ + (k - KP)];
                else if (k == KP + NB_)  x = vt[n];
            }
            u.s[i] = f2bf(x);
        }
        *(uint4*)(bt + (size_t)n * KE + k0) = u.v;   // 16B aligned
    } else {
        int i = (g - 336 - 81 * 28) * 256 + t;       // < VPAD*32
        int v = i >> 5, j = i & 31;
        float x = (j < 24 && v < V_) ? lw[(size_t)v * 24 + j] : 0.f;
        ushort hi = f2bf(x);
        w_hi[i] = hi;
        w_lo[i] = f2bf(x - bf2f(hi));
    }
}

// ---------------------------------------------------------------------------
// K2: per-batch — jsp reduce (folded, same summation order -> bit-identical),
// Rodrigues, joints, pose_feat (bf16), FK, then write A_rel TRANSPOSED as
// bf16 hi/lo: aT[b][e*32+j] = A_rel[b][j][e] (e<12, j<24).
// ---------------------------------------------------------------------------
__global__ __launch_bounds__(64) void k_pose(const float* __restrict__ shape,
                                             const float* __restrict__ body_pose,
                                             const float* __restrict__ pelvis,
                                             const float* __restrict__ jsp,
                                             ushort* __restrict__ pfext,
                                             ushort* __restrict__ aT_hi,
                                             ushort* __restrict__ aT_lo,
                                             int Breal) {
    int b = blockIdx.x;
    int t = threadIdx.x;
    if (b >= Breal) {
        uint32_t* pz = (uint32_t*)(pfext + (size_t)b * KE);
        for (int i = t; i < KE / 2; i += 64) pz[i] = 0;
        return;
    }
    __shared__ float js_s[792];
    __shared__ float Rs[24][9];
    __shared__ float Js[24][3];
    __shared__ float As[24][12];

    // folded k_jred: js_s[j*33+i] = sum_c jsp[(j*14+c)*33+i]  (c ascending)
    for (int idx = t; idx < 792; idx += 64) {
        int j = idx / 33, i = idx - j * 33;
        float s = 0.f;
#pragma unroll
        for (int c = 0; c < 14; c++) s += jsp[(size_t)(j * 14 + c) * 33 + i];
        js_s[idx] = s;
    }
    __syncthreads();

    if (t < 24) {
        float rx, ry, rz;
        if (t == 0) {
            rx = pelvis[b * 3 + 0]; ry = pelvis[b * 3 + 1]; rz = pelvis[b * 3 + 2];
        } else {
            const float* p = body_pose + ((size_t)b * 23 + (t - 1)) * 3;
            rx = p[0]; ry = p[1]; rz = p[2];
        }
        float th = sqrtf(rx * rx + ry * ry + rz * rz + 1e-8f);
        float inv = 1.f / th;
        float x = rx * inv, y = ry * inv, z = rz * inv;
        float c = cosf(th), s = sinf(th), omc = 1.f - c;
        float R[9];
        R[0] = c + omc * x * x;     R[1] = omc * x * y - s * z; R[2] = omc * x * z + s * y;
        R[3] = omc * y * x + s * z; R[4] = c + omc * y * y;     R[5] = omc * y * z - s * x;
        R[6] = omc * z * x - s * y; R[7] = omc * z * y + s * x; R[8] = c + omc * z * z;
#pragma unroll
        for (int e = 0; e < 9; e++) Rs[t][e] = R[e];

        const float* jsj = js_s + t * 33;
        float sh[10];
#pragma unroll
        for (int l = 0; l < 10; l++) sh[l] = shape[b * 10 + l];
#pragma unroll
        for (int c2 = 0; c2 < 3; c2++) {
            float a = jsj[c2];
#pragma unroll
            for (int l = 0; l < 10; l++) a += sh[l] * jsj[3 + c2 * 10 + l];
            Js[t][c2] = a;
        }
        ushort* pf = pfext + (size_t)b * KE;
        if (t >= 1) {
#pragma unroll
            for (int e = 0; e < 9; e++) {
                float v = R[e] - ((e == 0 || e == 4 || e == 8) ? 1.f : 0.f);
                pf[(t - 1) * 9 + e] = f2bf(v);
            }
        } else {
            for (int l = 0; l < 10; l++) pf[KP + l] = f2bf(sh[l]);
            pf[KP + NB_] = 0x3F80;                                   // 1.0 bf16
            for (int k = KP + NB_ + 1; k < KE; k++) pf[k] = 0;
        }
    }
    __syncthreads();

    if (t < 12) {
        int row = t >> 2, col = t & 3;
        As[0][t] = (col < 3) ? Rs[0][row * 3 + col] : Js[0][row];
    }
    __syncthreads();
    const int par[24] = {-1,0,0,0,1,2,3,4,5,6,7,8,9,9,9,12,13,14,16,17,18,19,20,21};
#pragma unroll 1
    for (int j = 1; j < 24; j++) {
        int p = par[j];
        float val = 0.f;
        if (t < 12) {
            int row = t >> 2, col = t & 3;
            if (col < 3) {
                val = As[p][row * 4 + 0] * Rs[j][0 * 3 + col]
                    + As[p][row * 4 + 1] * Rs[j][1 * 3 + col]
                    + As[p][row * 4 + 2] * Rs[j][2 * 3 + col];
            } else {
                float relx = Js[j][0] - Js[p][0];
                float rely = Js[j][1] - Js[p][1];
                float relz = Js[j][2] - Js[p][2];
                val = As[p][row * 4 + 0] * relx + As[p][row * 4 + 1] * rely
                    + As[p][row * 4 + 2] * relz + As[p][row * 4 + 3];
            }
        }
        __syncthreads();
        if (t < 12) As[j][t] = val;
        __syncthreads();
    }
    // finalize t_corr in place: As[j][x*4+3] = t - R*joint
    if (t < 24) {
        float tc[3];
#pragma unroll
        for (int row = 0; row < 3; row++) {
            float r0 = As[t][row * 4 + 0], r1 = As[t][row * 4 + 1], r2 = As[t][row * 4 + 2];
            tc[row] = As[t][row * 4 + 3] - (r0 * Js[t][0] + r1 * Js[t][1] + r2 * Js[t][2]);
        }
        As[t][3] = tc[0]; As[t][7] = tc[1]; As[t][11] = tc[2];
    }
    __syncthreads();
    // aT[e*32+j] = As[j][e], hi/lo bf16 (e<12, j<24; else 0)
    ushort* dh = aT_hi + (size_t)b * 512;
    ushort* dl = aT_lo + (size_t)b * 512;
    for (int i = t; i < 512; i += 64) {
        int e = i >> 5, j = i & 31;
        float val = (e < 12 && j < 24) ? As[j][e] : 0.f;
        ushort hi = f2bf(val);
        dh[i] = hi;
        dl[i] = f2bf(val - bf2f(hi));
    }
}

// ---------------------------------------------------------------------------
// K3+K4 fused v4: R1-measured-best structure (64v x 64b tile, 2D grid, block
// barrier, scalar LDS scatter at pitch 201, no stage-2 prefetch, W-frags
// loaded after the barrier) with ONE change: stage 1 is N-SPLIT across waves.
//   Wave wv owns bt rows nbase+wv*48..+47 for ALL 64 batches:
//     21 disjoint bt loads + 28 pfext loads (28 KB, L1-broadcast) = 49 load
//     instrs/wave vs 91 before (all 4 waves redundantly loading all of bt).
//   Same 84 MFMAs, same ks-ascending accumulation -> bit-identical v_posed.
//   Scatter: posed[g*16+m][wv*48 + f*16 + quad*4 + r] = acc[f][g][r].
//   Cross-wave LDS rows -> the (R1-proven) __syncthreads covers it.
// Stage 2: R1-identical (wave wv reads rows wv*16+bb, all 192 cols).
// ---------------------------------------------------------------------------
__global__ __launch_bounds__(256) void k_fused(const ushort* __restrict__ bt,
                                               const ushort* __restrict__ pfext,
                                               const ushort* __restrict__ aT_hi,
                                               const ushort* __restrict__ aT_lo,
                                               const ushort* __restrict__ w_hi,
                                               const ushort* __restrict__ w_lo,
                                               const float* __restrict__ trans,
                                               float* __restrict__ vert,
                                               int Breal) {
    int lane = threadIdx.x & 63;
    int wv   = threadIdx.x >> 6;
    int quad = lane >> 4;
    int m    = lane & 15;
    int vtile = blockIdx.x;                  // 0..107
    int nbase = vtile * 192;
    int bblk  = blockIdx.y * 64;             // block's 64 batches
    int bbase = bblk + wv * 16;              // wave's stage-2 batches

    __shared__ float posed[64][LDP];

    // ---- stage 1: v_posed GEMM, n-split (48n x 64b per wave) ----
    f32x4 acc[3][4];
#pragma unroll
    for (int f = 0; f < 3; f++)
#pragma unroll
        for (int gq = 0; gq < 4; gq++) acc[f][gq] = (f32x4){0.f, 0.f, 0.f, 0.f};

    const ushort* ap = bt + (size_t)(nbase + wv * 48 + m) * KE + quad * 8;
    const ushort* bp = pfext + (size_t)(bblk + m) * KE + quad * 8;
#pragma unroll 2
    for (int ks = 0; ks < 7; ks++) {
        bf16x8 av[3], bv[4];
#pragma unroll
        for (int f = 0; f < 3; f++)
            av[f] = *(const bf16x8*)(ap + (size_t)(f * 16) * KE + ks * 32);
#pragma unroll
        for (int gq = 0; gq < 4; gq++)
            bv[gq] = *(const bf16x8*)(bp + (size_t)(gq * 16) * KE + ks * 32);
#pragma unroll
        for (int f = 0; f < 3; f++)
#pragma unroll
            for (int gq = 0; gq < 4; gq++)
                acc[f][gq] = __builtin_amdgcn_mfma_f32_16x16x32_bf16(av[f], bv[gq], acc[f][gq], 0, 0, 0);
    }
    // scalar scatter (R1-proven): row = batch g*16+m, col = n-local
#pragma unroll
    for (int f = 0; f < 3; f++)
#pragma unroll
        for (int gq = 0; gq < 4; gq++) {
            float* dst = &posed[gq * 16 + m][wv * 48 + f * 16 + quad * 4];
            dst[0] = acc[f][gq][0]; dst[1] = acc[f][gq][1];
            dst[2] = acc[f][gq][2]; dst[3] = acc[f][gq][3];
        }
    __syncthreads();

    // ---- stage 2: LBS (R1-identical) ----
    bf16x8 Wh[4], Wl[4];
#pragma unroll
    for (int i = 0; i < 4; i++) {
        size_t offw = (size_t)((vtile * 4 + i) * 16 + m) * 32 + quad * 8;
        Wh[i] = *(const bf16x8*)(w_hi + offw);
        Wl[i] = *(const bf16x8*)(w_lo + offw);
    }

#pragma unroll 1
    for (int bb = 0; bb < 16; bb++) {
        int b = bbase + bb;
        if (b >= Breal) break;
        size_t aoff = (size_t)b * 512 + m * 32 + quad * 8;
        bf16x8 Ah = *(const bf16x8*)(aT_hi + aoff);
        bf16x8 Al = *(const bf16x8*)(aT_lo + aoff);
        float tq = (quad < 3) ? trans[b * 3 + quad] : 0.f;
        const float* pr = &posed[wv * 16 + bb][0];
        float* vrow = vert + (size_t)b * N3;
#pragma unroll
        for (int i = 0; i < 4; i++) {
            int vloc = i * 16 + m;
            int v = vtile * 64 + vloc;
            float p0 = pr[vloc * 3 + 0];
            float p1 = pr[vloc * 3 + 1];
            float p2 = pr[vloc * 3 + 2];
            f32x4 a2 = (f32x4){0.f, 0.f, 0.f, 0.f};
            a2 = __builtin_amdgcn_mfma_f32_16x16x32_bf16(Ah, Wh[i], a2, 0, 0, 0);
            a2 = __builtin_amdgcn_mfma_f32_16x16x32_bf16(Al, Wh[i], a2, 0, 0, 0);
            a2 = __builtin_amdgcn_mfma_f32_16x16x32_bf16(Ah, Wl[i], a2, 0, 0, 0);
            float res = a2[0] * p0 + a2[1] * p1 + a2[2] * p2 + a2[3] + tq;
            if (quad < 3 && v < V_)
                vrow[3 * v + quad] = res;
        }
    }
}

// ---------------------------------------------------------------------------
extern "C" void kernel_launch(void* const* d_in, const int* in_sizes, int n_in,
                              void* d_out, int out_size, void* d_ws, size_t ws_size,
                              hipStream_t stream) {
    const float* shape = (const float*)d_in[0];
    const float* bpose = (const float*)d_in[1];
    const float* pelv  = (const float*)d_in[2];
    const float* trans = (const float*)d_in[3];
    const float* vt    = (const float*)d_in[4];
    const float* sd    = (const float*)d_in[5];
    const float* pd    = (const float*)d_in[6];
    const float* lw    = (const float*)d_in[7];
    const float* jr    = (const float*)d_in[8];
    float* out = (float*)d_out;

    int B    = in_sizes[0] / NB_;          // batch from shape (B,10)
    int Bpad = (B + 63) & ~63;

    char* ws = (char*)d_ws;
    size_t off = 0;
    auto alloc = [&](size_t bytes) { char* p = ws + off; off += (bytes + 255) & ~(size_t)255; return p; };
    float*  jsp   = (float*) alloc(24 * 14 * 33 * 4);
    ushort* pfext = (ushort*)alloc((size_t)Bpad * KE * 2);
    ushort* aT_hi = (ushort*)alloc((size_t)B * 512 * 2);
    ushort* aT_lo = (ushort*)alloc((size_t)B * 512 * 2);
    ushort* w_hi  = (ushort*)alloc((size_t)VPAD * 32 * 2);
    ushort* w_lo  = (ushort*)alloc((size_t)VPAD * 32 * 2);
    ushort* bt    = (ushort*)alloc((size_t)NPAD * KE * 2);

    k_pre<<<336 + 81 * 28 + VPAD * 32 / 256, 256, 0, stream>>>(jr, vt, sd, pd, lw,
                                                               jsp, bt, w_hi, w_lo);
    k_pose<<<Bpad, 64, 0, stream>>>(shape, bpose, pelv, jsp, pfext, aT_hi, aT_lo, B);
    k_fused<<<dim3(108, Bpad / 64), 256, 0, stream>>>(bt, pfext, aT_hi, aT_lo,
                                                      w_hi, w_lo, trans, out, B);
}